// Round 9
// baseline (447.677 us; speedup 1.0000x reference)
//
#include <hip/hip_runtime.h>
#include <math.h>
#include <stdint.h>

#define B_ 4
#define L_ 2048
#define D_ 1024
#define H_ 16

typedef __attribute__((ext_vector_type(4))) float f32x4;
typedef __attribute__((ext_vector_type(2))) float f32x2;
typedef __attribute__((ext_vector_type(8))) short s16x8;
typedef __attribute__((ext_vector_type(4))) short s16x4;
typedef __attribute__((ext_vector_type(4))) unsigned short u16x4;
typedef __attribute__((ext_vector_type(4))) unsigned int u32x4;
typedef __attribute__((ext_vector_type(2))) __bf16 bf16x2;

__device__ __forceinline__ unsigned short f2bf(float f) {
  unsigned int u = __float_as_uint(f);
  u += 0x7fffu + ((u >> 16) & 1u);  // RNE
  return (unsigned short)(u >> 16);
}
__device__ __forceinline__ float b2f(unsigned short s) {
  return __uint_as_float(((unsigned int)s) << 16);
}
// packed f32x2 -> bf16x2 (RTNE); lowers to v_cvt_pk_bf16_f32 on gfx950
__device__ __forceinline__ unsigned int pk2(float a, float b) {
  f32x2 v;
  v[0] = a;
  v[1] = b;
  bf16x2 r = __builtin_convertvector(v, bf16x2);
  return __builtin_bit_cast(unsigned int, r);
}
// silu via fast rcp (1-ulp)
__device__ __forceinline__ float silu_fast(float v) {
  return v * __builtin_amdgcn_rcpf(1.0f + __expf(-v));
}
// async global->LDS DMA, 16B per lane; lds dest = wave-uniform base + lane*16
__device__ __forceinline__ void gl_lds16(const void* g, void* l) {
  __builtin_amdgcn_global_load_lds(
      (__attribute__((address_space(1))) void*)(uintptr_t)g,
      (__attribute__((address_space(3))) void*)(uint32_t)(uintptr_t)l, 16, 0, 0);
}

// ---------------------------------------------------------------------------
// Merged prep: conv_x (8192 blocks) | trans_w Wqkuv (1024) | trans_w Wout
// (256) | rope_tab (256) | amask f32->bf16 (16384).  One launch.
// amask bf16: halves the L1 line footprint of attn's dominant mask gather
// (row span 256B->128B); values like 1.0 are exact in bf16.
// ---------------------------------------------------------------------------
__global__ __launch_bounds__(256) void prep(const float* __restrict__ x,
                                            unsigned short* __restrict__ xb,
                                            const float* __restrict__ Wqkuv,
                                            unsigned short* __restrict__ Wt,
                                            const float* __restrict__ Wout,
                                            unsigned short* __restrict__ Wot,
                                            f32x2* __restrict__ tab,
                                            const float* __restrict__ amask,
                                            unsigned short* __restrict__ amb) {
  const int bid = blockIdx.x;
  const int tid = threadIdx.x;
  if (bid < 8192) {
    // conv_x: fp32 -> bf16 (x), 4 elems/thread
    int i = bid * 256 + tid;
    f32x4 v = *(const f32x4*)(x + (size_t)i * 4);
    u16x4 o;
#pragma unroll
    for (int j = 0; j < 4; ++j) o[j] = f2bf(v[j]);
    *(u16x4*)(xb + (size_t)i * 4) = o;
  } else if (bid < 9472) {
    // W[K][N] fp32 -> Wt[N][K] bf16 (LDS tile transpose)
    __shared__ float T[64][65];
    const float* W;
    unsigned short* Wd;
    int K, N, bx, by;
    if (bid < 9216) {
      int e = bid - 8192;  // grid (64,16) over (N=4096,K=1024)
      W = Wqkuv; Wd = Wt; K = 1024; N = 4096; bx = e & 63; by = e >> 6;
    } else {
      int e = bid - 9216;  // grid (16,16) over (N=1024,K=1024)
      W = Wout; Wd = Wot; K = 1024; N = 1024; bx = e & 15; by = e >> 4;
    }
    const int k0 = by * 64, n0 = bx * 64;
#pragma unroll
    for (int i = 0; i < 16; ++i) {
      int e = tid + i * 256;
      int r = e >> 6, c = e & 63;
      T[r][c] = W[(size_t)(k0 + r) * N + n0 + c];
    }
    __syncthreads();
#pragma unroll
    for (int i = 0; i < 16; ++i) {
      int e = tid + i * 256;
      int r = e >> 6, c = e & 63;
      Wd[(size_t)(n0 + r) * K + k0 + c] = f2bf(T[c][r]);
    }
  } else if (bid < 9728) {
    // rope_tab: cos/sin table [L][32]
    int i = (bid - 9472) * 256 + tid;  // L_*32
    int l = i >> 5, j = i & 31;
    float inv = expf(-(float)j * (9.210340371976184f / 32.0f));  // 10000^(-j/32)
    float ang = (float)l * inv;
    f32x2 cs;
    cs[0] = cosf(ang);
    cs[1] = sinf(ang);
    tab[i] = cs;
  } else {
    // amask fp32 -> bf16, 4 elems/thread (B*L*L = 16.7M elems, 16384 blocks)
    int i = (bid - 9728) * 256 + tid;
    f32x4 v = *(const f32x4*)(amask + (size_t)i * 4);
    u16x4 o;
#pragma unroll
    for (int j = 0; j < 4; ++j) o[j] = f2bf(v[j]);
    *(u16x4*)(amb + (size_t)i * 4) = o;
  }
}

// ---------------------------------------------------------------------------
// bf16 MFMA GEMM 256x256 8-phase, counted-vmcnt (T4) + fused RoPE epilogue
// (unchanged from round 8).
// ---------------------------------------------------------------------------
template <int MODE>
__global__ __launch_bounds__(512) void gemm_bf16(const unsigned short* __restrict__ A,
                                                 const unsigned short* __restrict__ Bt,
                                                 void* __restrict__ Cp,
                                                 const f32x2* __restrict__ tab,
                                                 int M, int N, int K) {
  alignas(16) __shared__ unsigned short Ash[2][256][64];
  alignas(16) __shared__ unsigned short Bsh[2][256][64];
  const int tid = threadIdx.x;
  const int lane = tid & 63, w = tid >> 6;
  const int quad = lane >> 4, l15 = lane & 15;
  const int wm = w >> 2, wn = w & 3;  // 2 x 4 wave grid
  // XCD swizzle: physical wgid -> chunked logical id (8 XCDs round-robin)
  const int nwg = gridDim.x * gridDim.y;
  const int wgid = blockIdx.y * gridDim.x + blockIdx.x;
  const int swz = (wgid & 7) * (nwg >> 3) + (wgid >> 3);
  const int m0 = (swz / gridDim.x) * 256, n0 = (swz % gridDim.x) * 256;

  const int s_sub = lane >> 3;           // 0..7 row-within-8
  const int s_src = (lane & 7) ^ s_sub;  // source k-chunk (XOR-8 swizzle)

  auto stageA = [&](int k0, int qa, unsigned short(*dst)[64]) {
#pragma unroll
    for (int g = 0; g < 2; ++g) {
      int rb = qa * 64 + g * 128 + w * 8;  // wave-uniform
      gl_lds16(A + (size_t)(m0 + rb + s_sub) * K + k0 + s_src * 8, &dst[rb][0]);
    }
  };
  auto stageB = [&](int k0, int qb, unsigned short(*dst)[64]) {
#pragma unroll
    for (int g = 0; g < 2; ++g) {
      int rb = qb * 32 + g * 128 + (w >> 2) * 64 + (w & 3) * 8;  // wave-uniform
      gl_lds16(Bt + (size_t)(n0 + rb + s_sub) * K + k0 + s_src * 8, &dst[rb][0]);
    }
  };

  f32x4 acc[8][4] = {};
  const int NT = K / 64;

  stageA(0, 0, Ash[0]);
  stageB(0, 0, Bsh[0]);
  stageA(0, 1, Ash[0]);
  stageB(0, 1, Bsh[0]);
  asm volatile("s_waitcnt vmcnt(4)" ::: "memory");
  __builtin_amdgcn_s_barrier();
  __builtin_amdgcn_sched_barrier(0);

  for (int t = 0; t < NT; ++t) {
    const int c = t & 1;
#pragma unroll
    for (int p = 0; p < 4; ++p) {
      const int qa = p & 1, qb = p >> 1;
      s16x8 af[4][2], bf[2][2];
#pragma unroll
      for (int i = 0; i < 4; ++i)
#pragma unroll
        for (int ks = 0; ks < 2; ++ks)
          af[i][ks] = *(const s16x8*)&Ash[c][wm * 128 + (qa * 4 + i) * 16 + l15]
                                           [((ks * 4 + quad) ^ (l15 & 7)) * 8];
#pragma unroll
      for (int jn = 0; jn < 2; ++jn)
#pragma unroll
        for (int ks = 0; ks < 2; ++ks)
          bf[jn][ks] = *(const s16x8*)&Bsh[c][wn * 64 + (qb * 2 + jn) * 16 + l15]
                                            [((ks * 4 + quad) ^ (l15 & 7)) * 8];
      if (t + 1 < NT) {
        if (p == 0) stageA((t + 1) * 64, 0, Ash[c ^ 1]);
        if (p == 1) stageB((t + 1) * 64, 0, Bsh[c ^ 1]);
        if (p == 2) stageA((t + 1) * 64, 1, Ash[c ^ 1]);
        if (p == 3) stageB((t + 1) * 64, 1, Bsh[c ^ 1]);
      }
      __builtin_amdgcn_sched_barrier(0);
      __builtin_amdgcn_s_barrier();
      __builtin_amdgcn_sched_barrier(0);
      __builtin_amdgcn_s_setprio(1);
#pragma unroll
      for (int i = 0; i < 4; ++i)
#pragma unroll
        for (int jn = 0; jn < 2; ++jn)
#pragma unroll
          for (int ks = 0; ks < 2; ++ks)
            acc[qa * 4 + i][qb * 2 + jn] = __builtin_amdgcn_mfma_f32_16x16x32_bf16(
                af[i][ks], bf[jn][ks], acc[qa * 4 + i][qb * 2 + jn], 0, 0, 0);
      __builtin_amdgcn_s_setprio(0);
      __builtin_amdgcn_sched_barrier(0);
      if (t + 1 < NT) {
        if (p != 2) asm volatile("s_waitcnt vmcnt(4)" ::: "memory");
      } else {
        if (p == 0) asm volatile("s_waitcnt vmcnt(2)" ::: "memory");
        if (p == 1) asm volatile("s_waitcnt vmcnt(0)" ::: "memory");
      }
      __builtin_amdgcn_s_barrier();
      __builtin_amdgcn_sched_barrier(0);
    }
  }

  if (MODE == 1 && n0 < 2048) {
    // q/k quarters: silu then in-register RoPE, single bf16 quantization.
#pragma unroll
    for (int fm = 0; fm < 8; ++fm)
#pragma unroll
      for (int reg = 0; reg < 4; ++reg) {
        int rg = m0 + wm * 128 + fm * 16 + quad * 4 + reg;
        int l = rg & (L_ - 1);
        f32x2 cs0 = tab[l * 32 + l15];
        f32x2 cs1 = tab[l * 32 + 16 + l15];
        float v0 = silu_fast(acc[fm][0][reg]);
        float v1 = silu_fast(acc[fm][1][reg]);
        float v2 = silu_fast(acc[fm][2][reg]);
        float v3 = silu_fast(acc[fm][3][reg]);
        unsigned short* rowp = (unsigned short*)Cp + (size_t)rg * N + n0 + wn * 64 + l15;
        rowp[0] = f2bf(v0 * cs0[0] - v2 * cs0[1]);
        rowp[16] = f2bf(v1 * cs1[0] - v3 * cs1[1]);
        rowp[32] = f2bf(v2 * cs0[0] + v0 * cs0[1]);
        rowp[48] = f2bf(v3 * cs1[0] + v1 * cs1[1]);
      }
  } else {
#pragma unroll
    for (int fm = 0; fm < 8; ++fm)
#pragma unroll
      for (int fn = 0; fn < 4; ++fn)
#pragma unroll
        for (int reg = 0; reg < 4; ++reg) {
          int rg = m0 + wm * 128 + fm * 16 + quad * 4 + reg;
          int cg = n0 + wn * 64 + fn * 16 + l15;
          float v = acc[fm][fn][reg];
          if (MODE == 1) {
            ((unsigned short*)Cp)[(size_t)rg * N + cg] = f2bf(silu_fast(v));
          } else {
            ((float*)Cp)[(size_t)rg * N + cg] = v;
          }
        }
  }
}

// ---------------------------------------------------------------------------
// bf16 MFMA GEMM 128x128 (m97-structure + XCD swizzle) — gemm2.
// ---------------------------------------------------------------------------
template <int MODE>
__global__ __launch_bounds__(256) void gemm128_bf16(const unsigned short* __restrict__ A,
                                                    const unsigned short* __restrict__ Bt,
                                                    void* __restrict__ Cp,
                                                    int M, int N, int K) {
  alignas(16) __shared__ unsigned short As[128][32];
  alignas(16) __shared__ unsigned short Bs[128][32];
  const int tid = threadIdx.x;
  const int lane = tid & 63, w = tid >> 6;
  const int quad = lane >> 4, l15 = lane & 15;
  const int wr = w >> 1, wc = w & 1;
  const int nwg = gridDim.x * gridDim.y;
  const int wgid = blockIdx.y * gridDim.x + blockIdx.x;
  const int swz = (wgid & 7) * (nwg >> 3) + (wgid >> 3);
  const int m0 = (swz / gridDim.x) * 128, n0 = (swz % gridDim.x) * 128;
  const int srow = lane >> 2;
  const int schunk = (lane & 3) ^ ((lane >> 3) & 3);
  const int fcol = (quad ^ ((l15 >> 1) & 3)) * 8;
  f32x4 acc[4][4] = {};
  for (int k0 = 0; k0 < K; k0 += 32) {
    __syncthreads();
#pragma unroll
    for (int i = 0; i < 2; ++i) {
      int r0 = (w * 2 + i) * 16;
      gl_lds16(A + (size_t)(m0 + r0 + srow) * K + k0 + schunk * 8, &As[r0][0]);
      gl_lds16(Bt + (size_t)(n0 + r0 + srow) * K + k0 + schunk * 8, &Bs[r0][0]);
    }
    __syncthreads();
    s16x8 af[4], bf[4];
#pragma unroll
    for (int mi = 0; mi < 4; ++mi) af[mi] = *(const s16x8*)&As[wr * 64 + mi * 16 + l15][fcol];
#pragma unroll
    for (int nj = 0; nj < 4; ++nj) bf[nj] = *(const s16x8*)&Bs[wc * 64 + nj * 16 + l15][fcol];
#pragma unroll
    for (int mi = 0; mi < 4; ++mi)
#pragma unroll
      for (int nj = 0; nj < 4; ++nj)
        acc[mi][nj] = __builtin_amdgcn_mfma_f32_16x16x32_bf16(af[mi], bf[nj], acc[mi][nj], 0, 0, 0);
  }
#pragma unroll
  for (int mi = 0; mi < 4; ++mi)
#pragma unroll
    for (int nj = 0; nj < 4; ++nj)
#pragma unroll
      for (int reg = 0; reg < 4; ++reg) {
        int rg = m0 + wr * 64 + mi * 16 + quad * 4 + reg;
        int cg = n0 + wc * 64 + nj * 16 + l15;
        float v = acc[mi][nj][reg];
        if (MODE == 1) {
          ((unsigned short*)Cp)[(size_t)rg * N + cg] = f2bf(silu_fast(v));
        } else {
          ((float*)Cp)[(size_t)rg * N + cg] = v;
        }
      }
}

// ---------------------------------------------------------------------------
// vt build: v_t[bh][64 d][Lperm] bf16 with the PV key permutation.
// ---------------------------------------------------------------------------
__global__ __launch_bounds__(256) void vt_build(const unsigned short* __restrict__ qk,
                                                unsigned short* __restrict__ vt) {
  alignas(16) __shared__ unsigned short Vsh[64][72];
  const int tid = threadIdx.x;
  const int bh = blockIdx.y, b = bh >> 4, h = bh & 15;
  const int l0 = blockIdx.x * 64;
#pragma unroll
  for (int i = 0; i < 2; ++i) {
    int ch = tid + i * 256;
    int row = ch >> 3, c8 = ch & 7;
    *(s16x8*)&Vsh[row][c8 * 8] =
        *(const s16x8*)(qk + (size_t)(b * L_ + l0 + row) * 4096 + 2048 + h * 64 + c8 * 8);
  }
  __syncthreads();
#pragma unroll
  for (int i = 0; i < 2; ++i) {
    int ch = tid + i * 256;
    int drow = ch >> 3, c8 = ch & 7;
    s16x8 o;
#pragma unroll
    for (int jj = 0; jj < 8; ++jj) {
      int pos = c8 * 8 + jj;  // 0..63 within tile
      int g = pos >> 5, p = pos & 31;
      int lk = g * 32 + ((p >> 2) & 1) * 16 + ((p >> 3) & 3) * 4 + (p & 3);
      o[jj] = (short)Vsh[lk][drow];
    }
    *(s16x8*)(vt + (size_t)(bh * 64 + drow) * 2048 + l0 + c8 * 8) = o;
  }
}

// ---------------------------------------------------------------------------
// Fused MFMA attention v10 = round-0 structure with BF16 amask loads.
// Theory: the wave-iter wall (~1100cy) is L1 line-request throughput:
// K 64 + V 64 + am4(f32) 128 + cm 16 lines/wave-iter x 4 waves ~ 1040
// requests/CU/iter at ~1/cy.  bf16 amask halves the dominant am4 term
// (row span 256B->128B).  Only the am4 load width + b2f changed.
// ---------------------------------------------------------------------------
__global__ __launch_bounds__(256) void attn_mfma(
    const unsigned short* __restrict__ qk, const unsigned short* __restrict__ vt,
    const unsigned short* __restrict__ amb, const float* __restrict__ cmask,
    const float* __restrict__ cbias, const float* __restrict__ gamma,
    const float* __restrict__ beta, unsigned short* __restrict__ attng) {
  alignas(16) __shared__ unsigned short Ks[64][64];   // [key][d], d-chunks XORed
  alignas(16) __shared__ unsigned short Vts[64][64];  // [d][key], key-chunks XORed
  const int tid = threadIdx.x;
  const int lane = tid & 63, w = tid >> 6;
  const int quad = lane >> 4, l15 = lane & 15;
  const int bh = blockIdx.y, b = bh >> 4, h = bh & 15;
  const int l0 = blockIdx.x * 128;
  const float cb = cbias[h];
  const int srow = lane >> 3;            // 0..7 within a 1KB DMA
  const int schunk = (lane & 7) ^ srow;  // source chunk for XOR-8 store

  // Hoist Q fragments for this wave's 32 q-rows (b-operand of S^T mfma)
  s16x8 qf[2][2];
  const unsigned short* abase[2];
#pragma unroll
  for (int qs = 0; qs < 2; ++qs) {
    int qg = l0 + w * 32 + qs * 16 + l15;
#pragma unroll
    for (int s = 0; s < 2; ++s)
      qf[qs][s] = *(const s16x8*)(qk + (size_t)(b * L_ + qg) * 4096 + h * 64 + s * 32 + quad * 8);
    abase[qs] = amb + ((size_t)b * L_ + qg) * L_;
  }
  const float* cbase = cmask + (size_t)b * L_;

  f32x4 oacc[2][4] = {};  // [qs][dt] C-layout: row=q=quad*4+reg, col=d=dt*16+l15

  for (int m0 = 0; m0 < L_; m0 += 64) {
    __syncthreads();  // prev-iter LDS reads complete before DMA overwrite
#pragma unroll
    for (int i = 0; i < 2; ++i) {  // wave w stages rows w*16+i*8 .. +7
      int r0 = w * 16 + i * 8;
      gl_lds16(qk + (size_t)(b * L_ + m0 + r0 + srow) * 4096 + 1024 + h * 64 + schunk * 8,
               &Ks[r0][0]);
      gl_lds16(vt + (size_t)(bh * 64 + r0 + srow) * 2048 + m0 + schunk * 8, &Vts[r0][0]);
    }
    // Masks: cmcb f32x4 (broadcast rows, cheap); am4 bf16 ushort4 (8B/lane)
    f32x4 cmcb[4];
    u16x4 am4[2][4];
#pragma unroll
    for (int kt = 0; kt < 4; ++kt)
      cmcb[kt] = *(const f32x4*)(cbase + m0 + kt * 16 + quad * 4) * cb;
#pragma unroll
    for (int qs = 0; qs < 2; ++qs)
#pragma unroll
      for (int kt = 0; kt < 4; ++kt)
        am4[qs][kt] = *(const u16x4*)(abase[qs] + m0 + kt * 16 + quad * 4);
    __syncthreads();  // vmcnt(0) drain -> DMA + mask loads complete

    // S^T = K @ Q^T over d=64 (two K=32 steps)
    f32x4 sacc[2][4] = {};  // [qs][kt]; C: key=quad*4+reg, q=l15
#pragma unroll
    for (int s = 0; s < 2; ++s) {
      s16x8 kf[4];
#pragma unroll
      for (int kt = 0; kt < 4; ++kt)
        kf[kt] = *(const s16x8*)&Ks[kt * 16 + l15][((s * 4 + quad) ^ (l15 & 7)) * 8];
      __builtin_amdgcn_s_setprio(1);
#pragma unroll
      for (int qs = 0; qs < 2; ++qs)
#pragma unroll
        for (int kt = 0; kt < 4; ++kt)
          sacc[qs][kt] = __builtin_amdgcn_mfma_f32_16x16x32_bf16(kf[kt], qf[qs][s],
                                                                 sacc[qs][kt], 0, 0, 0);
      __builtin_amdgcn_s_setprio(0);
    }

    // Epilogue -> P fragments packed as K=32 A-operands (kt pairs)
    s16x8 pf[2][2];
#pragma unroll
    for (int qs = 0; qs < 2; ++qs)
#pragma unroll
      for (int t = 0; t < 2; ++t) {
        u32x4 pw;
#pragma unroll
        for (int half = 0; half < 2; ++half) {
          int kt = 2 * t + half;
          float x[4];
#pragma unroll
          for (int r = 0; r < 4; ++r) {
            float v = fmaf(sacc[qs][kt][r], 0.125f, cmcb[kt][r]);
            v = silu_fast(v);
            x[r] = v * b2f(am4[qs][kt][r]);
          }
          pw[half * 2 + 0] = pk2(x[0], x[1]);
          pw[half * 2 + 1] = pk2(x[2], x[3]);
        }
        pf[qs][t] = __builtin_bit_cast(s16x8, pw);
      }

    // O += P @ V, K=32 per group (vt key-permuted to match P's lane layout)
#pragma unroll
    for (int dt = 0; dt < 4; ++dt)
#pragma unroll
      for (int t = 0; t < 2; ++t) {
        s16x8 vf = *(const s16x8*)&Vts[dt * 16 + l15][((t * 4 + quad) ^ (l15 & 7)) * 8];
        __builtin_amdgcn_s_setprio(1);
#pragma unroll
        for (int qs = 0; qs < 2; ++qs)
          oacc[qs][dt] = __builtin_amdgcn_mfma_f32_16x16x32_bf16(pf[qs][t], vf,
                                                                 oacc[qs][dt], 0, 0, 0);
        __builtin_amdgcn_s_setprio(0);
      }
  }

  // LayerNorm over d=64 + u-gate + store
#pragma unroll
  for (int qs = 0; qs < 2; ++qs) {
    float sm[4], sq[4];
#pragma unroll
    for (int reg = 0; reg < 4; ++reg) {
      float s1 = 0.f, s2 = 0.f;
#pragma unroll
      for (int dt = 0; dt < 4; ++dt) {
        float v = oacc[qs][dt][reg];
        s1 += v;
        s2 += v * v;
      }
      sm[reg] = s1;
      sq[reg] = s2;
    }
#pragma unroll
    for (int m = 1; m < 16; m <<= 1) {
#pragma unroll
      for (int reg = 0; reg < 4; ++reg) {
        sm[reg] += __shfl_xor(sm[reg], m);
        sq[reg] += __shfl_xor(sq[reg], m);
      }
    }
    float mu[4], rs[4];
#pragma unroll
    for (int reg = 0; reg < 4; ++reg) {
      mu[reg] = sm[reg] * (1.0f / 64.0f);
      float var = sq[reg] * (1.0f / 64.0f) - mu[reg] * mu[reg];
      rs[reg] = rsqrtf(var + 1e-5f);
    }
#pragma unroll
    for (int dt = 0; dt < 4; ++dt) {
      float g = gamma[dt * 16 + l15], be = beta[dt * 16 + l15];
#pragma unroll
      for (int reg = 0; reg < 4; ++reg) {
        int rowg = l0 + w * 32 + qs * 16 + quad * 4 + reg;
        int colg = dt * 16 + l15;
        float v = (oacc[qs][dt][reg] - mu[reg]) * rs[reg] * g + be;
        float u = b2f(qk[(size_t)(b * L_ + rowg) * 4096 + 3072 + h * 64 + colg]);
        attng[(size_t)(b * L_ + rowg) * 1024 + h * 64 + colg] = f2bf(v * u);
      }
    }
  }
}

extern "C" void kernel_launch(void* const* d_in, const int* in_sizes, int n_in,
                              void* d_out, int out_size, void* d_ws, size_t ws_size,
                              hipStream_t stream) {
  const float* x = (const float*)d_in[0];
  const float* amask = (const float*)d_in[1];
  const float* cmask = (const float*)d_in[2];
  const float* Wqkuv = (const float*)d_in[3];
  const float* Wout = (const float*)d_in[4];
  const float* gamma = (const float*)d_in[5];
  const float* beta = (const float*)d_in[6];
  const float* cbias = (const float*)d_in[7];
  float* out = (float*)d_out;

  char* ws = (char*)d_ws;
  unsigned short* qkuv_bf = (unsigned short*)ws;                    // 64 MB
  unsigned short* vt = (unsigned short*)(ws + ((size_t)64 << 20));  // 16 MB
  unsigned short* xbf = (unsigned short*)(ws + ((size_t)80 << 20));  // 16 MB
  unsigned short* Wt = (unsigned short*)(ws + ((size_t)96 << 20));   // 8 MB
  unsigned short* Wot = (unsigned short*)(ws + ((size_t)104 << 20)); // 2 MB
  unsigned short* attng = (unsigned short*)(ws + ((size_t)106 << 20)); // 16 MB
  f32x2* tab = (f32x2*)(ws + ((size_t)122 << 20));                   // 0.5 MB
  unsigned short* amb = (unsigned short*)(ws + ((size_t)128 << 20)); // 32 MB

  prep<<<26112, 256, 0, stream>>>(x, xbf, Wqkuv, Wt, Wout, Wot, tab, amask, amb);

  gemm_bf16<1><<<dim3(4096 / 256, 8192 / 256), 512, 0, stream>>>(xbf, Wt, qkuv_bf, tab,
                                                                 B_ * L_, 4 * D_, D_);
  vt_build<<<dim3(L_ / 64, B_ * H_), 256, 0, stream>>>(qkuv_bf, vt);
  attn_mfma<<<dim3(L_ / 128, B_ * H_), 256, 0, stream>>>(qkuv_bf, vt, amb, cmask, cbias,
                                                         gamma, beta, attng);
  gemm128_bf16<0><<<dim3(1024 / 128, 8192 / 128), 256, 0, stream>>>(attng, Wot, out,
                                                                    B_ * L_, D_, D_);
}

// Round 10
// 434.582 us; speedup vs baseline: 1.0301x; 1.0301x over previous
//
#include <hip/hip_runtime.h>
#include <math.h>
#include <stdint.h>

#define B_ 4
#define L_ 2048
#define D_ 1024
#define H_ 16

typedef __attribute__((ext_vector_type(4))) float f32x4;
typedef __attribute__((ext_vector_type(2))) float f32x2;
typedef __attribute__((ext_vector_type(8))) short s16x8;
typedef __attribute__((ext_vector_type(4))) short s16x4;
typedef __attribute__((ext_vector_type(4))) unsigned short u16x4;
typedef __attribute__((ext_vector_type(4))) unsigned int u32x4;
typedef __attribute__((ext_vector_type(2))) __bf16 bf16x2;

__device__ __forceinline__ unsigned short f2bf(float f) {
  unsigned int u = __float_as_uint(f);
  u += 0x7fffu + ((u >> 16) & 1u);  // RNE
  return (unsigned short)(u >> 16);
}
__device__ __forceinline__ float b2f(unsigned short s) {
  return __uint_as_float(((unsigned int)s) << 16);
}
// packed f32x2 -> bf16x2 (RTNE); lowers to v_cvt_pk_bf16_f32 on gfx950
__device__ __forceinline__ unsigned int pk2(float a, float b) {
  f32x2 v;
  v[0] = a;
  v[1] = b;
  bf16x2 r = __builtin_convertvector(v, bf16x2);
  return __builtin_bit_cast(unsigned int, r);
}
// silu via fast rcp (1-ulp)
__device__ __forceinline__ float silu_fast(float v) {
  return v * __builtin_amdgcn_rcpf(1.0f + __expf(-v));
}
// async global->LDS DMA, 16B per lane; lds dest = wave-uniform base + lane*16
__device__ __forceinline__ void gl_lds16(const void* g, void* l) {
  __builtin_amdgcn_global_load_lds(
      (__attribute__((address_space(1))) void*)(uintptr_t)g,
      (__attribute__((address_space(3))) void*)(uint32_t)(uintptr_t)l, 16, 0, 0);
}

// ---------------------------------------------------------------------------
// Merged prep: conv_x (8192 blocks) | trans_w Wqkuv (1024) | trans_w Wout
// (256) | rope_tab (256).  (amask conversion removed — round-9 showed it
// net-negative: attn -9.5us < prep +12us.)
// ---------------------------------------------------------------------------
__global__ __launch_bounds__(256) void prep(const float* __restrict__ x,
                                            unsigned short* __restrict__ xb,
                                            const float* __restrict__ Wqkuv,
                                            unsigned short* __restrict__ Wt,
                                            const float* __restrict__ Wout,
                                            unsigned short* __restrict__ Wot,
                                            f32x2* __restrict__ tab) {
  const int bid = blockIdx.x;
  const int tid = threadIdx.x;
  if (bid < 8192) {
    int i = bid * 256 + tid;
    f32x4 v = *(const f32x4*)(x + (size_t)i * 4);
    u16x4 o;
#pragma unroll
    for (int j = 0; j < 4; ++j) o[j] = f2bf(v[j]);
    *(u16x4*)(xb + (size_t)i * 4) = o;
  } else if (bid < 9472) {
    __shared__ float T[64][65];
    const float* W;
    unsigned short* Wd;
    int K, N, bx, by;
    if (bid < 9216) {
      int e = bid - 8192;
      W = Wqkuv; Wd = Wt; K = 1024; N = 4096; bx = e & 63; by = e >> 6;
    } else {
      int e = bid - 9216;
      W = Wout; Wd = Wot; K = 1024; N = 1024; bx = e & 15; by = e >> 4;
    }
    const int k0 = by * 64, n0 = bx * 64;
#pragma unroll
    for (int i = 0; i < 16; ++i) {
      int e = tid + i * 256;
      int r = e >> 6, c = e & 63;
      T[r][c] = W[(size_t)(k0 + r) * N + n0 + c];
    }
    __syncthreads();
#pragma unroll
    for (int i = 0; i < 16; ++i) {
      int e = tid + i * 256;
      int r = e >> 6, c = e & 63;
      Wd[(size_t)(n0 + r) * K + k0 + c] = f2bf(T[c][r]);
    }
  } else {
    int i = (bid - 9472) * 256 + tid;  // L_*32
    int l = i >> 5, j = i & 31;
    float inv = expf(-(float)j * (9.210340371976184f / 32.0f));
    float ang = (float)l * inv;
    f32x2 cs;
    cs[0] = cosf(ang);
    cs[1] = sinf(ang);
    tab[i] = cs;
  }
}

// ---------------------------------------------------------------------------
// bf16 MFMA GEMM 256x256 8-phase, counted-vmcnt (T4).  Three epilogues:
//   n0 <  2048 (q,k): fused silu+RoPE, single bf16 quantization -> qkuv
//   n0 <  3072 (v)  : fused silu + PV-key-permuted transpose -> vt DIRECTLY
//                     (replaces the vt_build kernel: acc[fm][fn][reg] holds 4
//                     consecutive l at one d; permutation 16h'+4q+j -> 8q+4h'+j
//                     with h'=(fm&1),q=quad,j=reg makes them 4 consecutive vt
//                     columns -> one u16x4 store).  qkuv v-quarter unused.
//   else      (u)  : silu -> qkuv
// ---------------------------------------------------------------------------
template <int MODE>
__global__ __launch_bounds__(512) void gemm_bf16(const unsigned short* __restrict__ A,
                                                 const unsigned short* __restrict__ Bt,
                                                 void* __restrict__ Cp,
                                                 unsigned short* __restrict__ vtp,
                                                 const f32x2* __restrict__ tab,
                                                 int M, int N, int K) {
  alignas(16) __shared__ unsigned short Ash[2][256][64];
  alignas(16) __shared__ unsigned short Bsh[2][256][64];
  const int tid = threadIdx.x;
  const int lane = tid & 63, w = tid >> 6;
  const int quad = lane >> 4, l15 = lane & 15;
  const int wm = w >> 2, wn = w & 3;  // 2 x 4 wave grid
  const int nwg = gridDim.x * gridDim.y;
  const int wgid = blockIdx.y * gridDim.x + blockIdx.x;
  const int swz = (wgid & 7) * (nwg >> 3) + (wgid >> 3);
  const int m0 = (swz / gridDim.x) * 256, n0 = (swz % gridDim.x) * 256;

  const int s_sub = lane >> 3;           // 0..7 row-within-8
  const int s_src = (lane & 7) ^ s_sub;  // source k-chunk (XOR-8 swizzle)

  auto stageA = [&](int k0, int qa, unsigned short(*dst)[64]) {
#pragma unroll
    for (int g = 0; g < 2; ++g) {
      int rb = qa * 64 + g * 128 + w * 8;  // wave-uniform
      gl_lds16(A + (size_t)(m0 + rb + s_sub) * K + k0 + s_src * 8, &dst[rb][0]);
    }
  };
  auto stageB = [&](int k0, int qb, unsigned short(*dst)[64]) {
#pragma unroll
    for (int g = 0; g < 2; ++g) {
      int rb = qb * 32 + g * 128 + (w >> 2) * 64 + (w & 3) * 8;  // wave-uniform
      gl_lds16(Bt + (size_t)(n0 + rb + s_sub) * K + k0 + s_src * 8, &dst[rb][0]);
    }
  };

  f32x4 acc[8][4] = {};
  const int NT = K / 64;

  stageA(0, 0, Ash[0]);
  stageB(0, 0, Bsh[0]);
  stageA(0, 1, Ash[0]);
  stageB(0, 1, Bsh[0]);
  asm volatile("s_waitcnt vmcnt(4)" ::: "memory");
  __builtin_amdgcn_s_barrier();
  __builtin_amdgcn_sched_barrier(0);

  for (int t = 0; t < NT; ++t) {
    const int c = t & 1;
#pragma unroll
    for (int p = 0; p < 4; ++p) {
      const int qa = p & 1, qb = p >> 1;
      s16x8 af[4][2], bf[2][2];
#pragma unroll
      for (int i = 0; i < 4; ++i)
#pragma unroll
        for (int ks = 0; ks < 2; ++ks)
          af[i][ks] = *(const s16x8*)&Ash[c][wm * 128 + (qa * 4 + i) * 16 + l15]
                                           [((ks * 4 + quad) ^ (l15 & 7)) * 8];
#pragma unroll
      for (int jn = 0; jn < 2; ++jn)
#pragma unroll
        for (int ks = 0; ks < 2; ++ks)
          bf[jn][ks] = *(const s16x8*)&Bsh[c][wn * 64 + (qb * 2 + jn) * 16 + l15]
                                            [((ks * 4 + quad) ^ (l15 & 7)) * 8];
      if (t + 1 < NT) {
        if (p == 0) stageA((t + 1) * 64, 0, Ash[c ^ 1]);
        if (p == 1) stageB((t + 1) * 64, 0, Bsh[c ^ 1]);
        if (p == 2) stageA((t + 1) * 64, 1, Ash[c ^ 1]);
        if (p == 3) stageB((t + 1) * 64, 1, Bsh[c ^ 1]);
      }
      __builtin_amdgcn_sched_barrier(0);
      __builtin_amdgcn_s_barrier();
      __builtin_amdgcn_sched_barrier(0);
      __builtin_amdgcn_s_setprio(1);
#pragma unroll
      for (int i = 0; i < 4; ++i)
#pragma unroll
        for (int jn = 0; jn < 2; ++jn)
#pragma unroll
          for (int ks = 0; ks < 2; ++ks)
            acc[qa * 4 + i][qb * 2 + jn] = __builtin_amdgcn_mfma_f32_16x16x32_bf16(
                af[i][ks], bf[jn][ks], acc[qa * 4 + i][qb * 2 + jn], 0, 0, 0);
      __builtin_amdgcn_s_setprio(0);
      __builtin_amdgcn_sched_barrier(0);
      if (t + 1 < NT) {
        if (p != 2) asm volatile("s_waitcnt vmcnt(4)" ::: "memory");
      } else {
        if (p == 0) asm volatile("s_waitcnt vmcnt(2)" ::: "memory");
        if (p == 1) asm volatile("s_waitcnt vmcnt(0)" ::: "memory");
      }
      __builtin_amdgcn_s_barrier();
      __builtin_amdgcn_sched_barrier(0);
    }
  }

  if (MODE == 1 && n0 < 2048) {
    // q/k: silu + in-register RoPE, single bf16 quantization
#pragma unroll
    for (int fm = 0; fm < 8; ++fm)
#pragma unroll
      for (int reg = 0; reg < 4; ++reg) {
        int rg = m0 + wm * 128 + fm * 16 + quad * 4 + reg;
        int l = rg & (L_ - 1);
        f32x2 cs0 = tab[l * 32 + l15];
        f32x2 cs1 = tab[l * 32 + 16 + l15];
        float v0 = silu_fast(acc[fm][0][reg]);
        float v1 = silu_fast(acc[fm][1][reg]);
        float v2 = silu_fast(acc[fm][2][reg]);
        float v3 = silu_fast(acc[fm][3][reg]);
        unsigned short* rowp = (unsigned short*)Cp + (size_t)rg * N + n0 + wn * 64 + l15;
        rowp[0] = f2bf(v0 * cs0[0] - v2 * cs0[1]);
        rowp[16] = f2bf(v1 * cs1[0] - v3 * cs1[1]);
        rowp[32] = f2bf(v2 * cs0[0] + v0 * cs0[1]);
        rowp[48] = f2bf(v3 * cs1[0] + v1 * cs1[1]);
      }
  } else if (MODE == 1 && n0 < 3072) {
    // v: silu + PV-key-permuted transpose directly into vt
    const int b = m0 >> 11;
    const int h = ((n0 - 2048) >> 6) + wn;  // head index
    const int bh = b * 16 + h;
#pragma unroll
    for (int fm = 0; fm < 8; ++fm) {
      const int lcol = (m0 & (L_ - 1)) + wm * 128 + (fm >> 1) * 32 + quad * 8 + (fm & 1) * 4;
#pragma unroll
      for (int fn = 0; fn < 4; ++fn) {
        const int dloc = fn * 16 + l15;
        u16x4 o;
#pragma unroll
        for (int reg = 0; reg < 4; ++reg) o[reg] = f2bf(silu_fast(acc[fm][fn][reg]));
        *(u16x4*)(vtp + (size_t)(bh * 64 + dloc) * 2048 + lcol) = o;
      }
    }
  } else {
#pragma unroll
    for (int fm = 0; fm < 8; ++fm)
#pragma unroll
      for (int fn = 0; fn < 4; ++fn)
#pragma unroll
        for (int reg = 0; reg < 4; ++reg) {
          int rg = m0 + wm * 128 + fm * 16 + quad * 4 + reg;
          int cg = n0 + wn * 64 + fn * 16 + l15;
          float v = acc[fm][fn][reg];
          if (MODE == 1) {
            ((unsigned short*)Cp)[(size_t)rg * N + cg] = f2bf(silu_fast(v));
          } else {
            ((float*)Cp)[(size_t)rg * N + cg] = v;
          }
        }
  }
}

// ---------------------------------------------------------------------------
// bf16 MFMA GEMM 128x128 (m97-structure + XCD swizzle) — gemm2.
// ---------------------------------------------------------------------------
template <int MODE>
__global__ __launch_bounds__(256) void gemm128_bf16(const unsigned short* __restrict__ A,
                                                    const unsigned short* __restrict__ Bt,
                                                    void* __restrict__ Cp,
                                                    int M, int N, int K) {
  alignas(16) __shared__ unsigned short As[128][32];
  alignas(16) __shared__ unsigned short Bs[128][32];
  const int tid = threadIdx.x;
  const int lane = tid & 63, w = tid >> 6;
  const int quad = lane >> 4, l15 = lane & 15;
  const int wr = w >> 1, wc = w & 1;
  const int nwg = gridDim.x * gridDim.y;
  const int wgid = blockIdx.y * gridDim.x + blockIdx.x;
  const int swz = (wgid & 7) * (nwg >> 3) + (wgid >> 3);
  const int m0 = (swz / gridDim.x) * 128, n0 = (swz % gridDim.x) * 128;
  const int srow = lane >> 2;
  const int schunk = (lane & 3) ^ ((lane >> 3) & 3);
  const int fcol = (quad ^ ((l15 >> 1) & 3)) * 8;
  f32x4 acc[4][4] = {};
  for (int k0 = 0; k0 < K; k0 += 32) {
    __syncthreads();
#pragma unroll
    for (int i = 0; i < 2; ++i) {
      int r0 = (w * 2 + i) * 16;
      gl_lds16(A + (size_t)(m0 + r0 + srow) * K + k0 + schunk * 8, &As[r0][0]);
      gl_lds16(Bt + (size_t)(n0 + r0 + srow) * K + k0 + schunk * 8, &Bs[r0][0]);
    }
    __syncthreads();
    s16x8 af[4], bf[4];
#pragma unroll
    for (int mi = 0; mi < 4; ++mi) af[mi] = *(const s16x8*)&As[wr * 64 + mi * 16 + l15][fcol];
#pragma unroll
    for (int nj = 0; nj < 4; ++nj) bf[nj] = *(const s16x8*)&Bs[wc * 64 + nj * 16 + l15][fcol];
#pragma unroll
    for (int mi = 0; mi < 4; ++mi)
#pragma unroll
      for (int nj = 0; nj < 4; ++nj)
        acc[mi][nj] = __builtin_amdgcn_mfma_f32_16x16x32_bf16(af[mi], bf[nj], acc[mi][nj], 0, 0, 0);
  }
#pragma unroll
  for (int mi = 0; mi < 4; ++mi)
#pragma unroll
    for (int nj = 0; nj < 4; ++nj)
#pragma unroll
      for (int reg = 0; reg < 4; ++reg) {
        int rg = m0 + wr * 64 + mi * 16 + quad * 4 + reg;
        int cg = n0 + wc * 64 + nj * 16 + l15;
        float v = acc[mi][nj][reg];
        if (MODE == 1) {
          ((unsigned short*)Cp)[(size_t)rg * N + cg] = f2bf(silu_fast(v));
        } else {
          ((float*)Cp)[(size_t)rg * N + cg] = v;
        }
      }
}

// ---------------------------------------------------------------------------
// Fused MFMA attention (round-0/8 baseline — protected at ~209us; f32 amask:
// round-9 showed bf16-amask's attn gain < its conversion cost).
// ---------------------------------------------------------------------------
__global__ __launch_bounds__(256) void attn_mfma(
    const unsigned short* __restrict__ qk, const unsigned short* __restrict__ vt,
    const float* __restrict__ amask, const float* __restrict__ cmask,
    const float* __restrict__ cbias, const float* __restrict__ gamma,
    const float* __restrict__ beta, unsigned short* __restrict__ attng) {
  alignas(16) __shared__ unsigned short Ks[64][64];   // [key][d], d-chunks XORed
  alignas(16) __shared__ unsigned short Vts[64][64];  // [d][key], key-chunks XORed
  const int tid = threadIdx.x;
  const int lane = tid & 63, w = tid >> 6;
  const int quad = lane >> 4, l15 = lane & 15;
  const int bh = blockIdx.y, b = bh >> 4, h = bh & 15;
  const int l0 = blockIdx.x * 128;
  const float cb = cbias[h];
  const int srow = lane >> 3;            // 0..7 within a 1KB DMA
  const int schunk = (lane & 7) ^ srow;  // source chunk for XOR-8 store

  s16x8 qf[2][2];
  const float* abase[2];
#pragma unroll
  for (int qs = 0; qs < 2; ++qs) {
    int qg = l0 + w * 32 + qs * 16 + l15;
#pragma unroll
    for (int s = 0; s < 2; ++s)
      qf[qs][s] = *(const s16x8*)(qk + (size_t)(b * L_ + qg) * 4096 + h * 64 + s * 32 + quad * 8);
    abase[qs] = amask + ((size_t)b * L_ + qg) * L_;
  }
  const float* cbase = cmask + (size_t)b * L_;

  f32x4 oacc[2][4] = {};  // [qs][dt] C-layout: row=q=quad*4+reg, col=d=dt*16+l15

  for (int m0 = 0; m0 < L_; m0 += 64) {
    __syncthreads();
#pragma unroll
    for (int i = 0; i < 2; ++i) {
      int r0 = w * 16 + i * 8;
      gl_lds16(qk + (size_t)(b * L_ + m0 + r0 + srow) * 4096 + 1024 + h * 64 + schunk * 8,
               &Ks[r0][0]);
      gl_lds16(vt + (size_t)(bh * 64 + r0 + srow) * 2048 + m0 + schunk * 8, &Vts[r0][0]);
    }
    f32x4 cmcb[4], am4[2][4];
#pragma unroll
    for (int kt = 0; kt < 4; ++kt)
      cmcb[kt] = *(const f32x4*)(cbase + m0 + kt * 16 + quad * 4) * cb;
#pragma unroll
    for (int qs = 0; qs < 2; ++qs)
#pragma unroll
      for (int kt = 0; kt < 4; ++kt)
        am4[qs][kt] = *(const f32x4*)(abase[qs] + m0 + kt * 16 + quad * 4);
    __syncthreads();

    f32x4 sacc[2][4] = {};
#pragma unroll
    for (int s = 0; s < 2; ++s) {
      s16x8 kf[4];
#pragma unroll
      for (int kt = 0; kt < 4; ++kt)
        kf[kt] = *(const s16x8*)&Ks[kt * 16 + l15][((s * 4 + quad) ^ (l15 & 7)) * 8];
      __builtin_amdgcn_s_setprio(1);
#pragma unroll
      for (int qs = 0; qs < 2; ++qs)
#pragma unroll
        for (int kt = 0; kt < 4; ++kt)
          sacc[qs][kt] = __builtin_amdgcn_mfma_f32_16x16x32_bf16(kf[kt], qf[qs][s],
                                                                 sacc[qs][kt], 0, 0, 0);
      __builtin_amdgcn_s_setprio(0);
    }

    s16x8 pf[2][2];
#pragma unroll
    for (int qs = 0; qs < 2; ++qs)
#pragma unroll
      for (int t = 0; t < 2; ++t) {
        u32x4 pw;
#pragma unroll
        for (int half = 0; half < 2; ++half) {
          int kt = 2 * t + half;
          float x[4];
#pragma unroll
          for (int r = 0; r < 4; ++r) {
            float v = fmaf(sacc[qs][kt][r], 0.125f, cmcb[kt][r]);
            v = silu_fast(v);
            x[r] = v * am4[qs][kt][r];
          }
          pw[half * 2 + 0] = pk2(x[0], x[1]);
          pw[half * 2 + 1] = pk2(x[2], x[3]);
        }
        pf[qs][t] = __builtin_bit_cast(s16x8, pw);
      }

#pragma unroll
    for (int dt = 0; dt < 4; ++dt)
#pragma unroll
      for (int t = 0; t < 2; ++t) {
        s16x8 vf = *(const s16x8*)&Vts[dt * 16 + l15][((t * 4 + quad) ^ (l15 & 7)) * 8];
        __builtin_amdgcn_s_setprio(1);
#pragma unroll
        for (int qs = 0; qs < 2; ++qs)
          oacc[qs][dt] = __builtin_amdgcn_mfma_f32_16x16x32_bf16(pf[qs][t], vf,
                                                                 oacc[qs][dt], 0, 0, 0);
        __builtin_amdgcn_s_setprio(0);
      }
  }

#pragma unroll
  for (int qs = 0; qs < 2; ++qs) {
    float sm[4], sq[4];
#pragma unroll
    for (int reg = 0; reg < 4; ++reg) {
      float s1 = 0.f, s2 = 0.f;
#pragma unroll
      for (int dt = 0; dt < 4; ++dt) {
        float v = oacc[qs][dt][reg];
        s1 += v;
        s2 += v * v;
      }
      sm[reg] = s1;
      sq[reg] = s2;
    }
#pragma unroll
    for (int m = 1; m < 16; m <<= 1) {
#pragma unroll
      for (int reg = 0; reg < 4; ++reg) {
        sm[reg] += __shfl_xor(sm[reg], m);
        sq[reg] += __shfl_xor(sq[reg], m);
      }
    }
    float mu[4], rs[4];
#pragma unroll
    for (int reg = 0; reg < 4; ++reg) {
      mu[reg] = sm[reg] * (1.0f / 64.0f);
      float var = sq[reg] * (1.0f / 64.0f) - mu[reg] * mu[reg];
      rs[reg] = rsqrtf(var + 1e-5f);
    }
#pragma unroll
    for (int dt = 0; dt < 4; ++dt) {
      float g = gamma[dt * 16 + l15], be = beta[dt * 16 + l15];
#pragma unroll
      for (int reg = 0; reg < 4; ++reg) {
        int rowg = l0 + w * 32 + qs * 16 + quad * 4 + reg;
        int colg = dt * 16 + l15;
        float v = (oacc[qs][dt][reg] - mu[reg]) * rs[reg] * g + be;
        float u = b2f(qk[(size_t)(b * L_ + rowg) * 4096 + 3072 + h * 64 + colg]);
        attng[(size_t)(b * L_ + rowg) * 1024 + h * 64 + colg] = f2bf(v * u);
      }
    }
  }
}

extern "C" void kernel_launch(void* const* d_in, const int* in_sizes, int n_in,
                              void* d_out, int out_size, void* d_ws, size_t ws_size,
                              hipStream_t stream) {
  const float* x = (const float*)d_in[0];
  const float* amask = (const float*)d_in[1];
  const float* cmask = (const float*)d_in[2];
  const float* Wqkuv = (const float*)d_in[3];
  const float* Wout = (const float*)d_in[4];
  const float* gamma = (const float*)d_in[5];
  const float* beta = (const float*)d_in[6];
  const float* cbias = (const float*)d_in[7];
  float* out = (float*)d_out;

  char* ws = (char*)d_ws;
  unsigned short* qkuv_bf = (unsigned short*)ws;                    // 64 MB
  unsigned short* vt = (unsigned short*)(ws + ((size_t)64 << 20));  // 16 MB
  unsigned short* xbf = (unsigned short*)(ws + ((size_t)80 << 20));  // 16 MB
  unsigned short* Wt = (unsigned short*)(ws + ((size_t)96 << 20));   // 8 MB
  unsigned short* Wot = (unsigned short*)(ws + ((size_t)104 << 20)); // 2 MB
  unsigned short* attng = (unsigned short*)(ws + ((size_t)106 << 20)); // 16 MB
  f32x2* tab = (f32x2*)(ws + ((size_t)122 << 20));                   // 0.5 MB

  prep<<<9728, 256, 0, stream>>>(x, xbf, Wqkuv, Wt, Wout, Wot, tab);

  gemm_bf16<1><<<dim3(4096 / 256, 8192 / 256), 512, 0, stream>>>(xbf, Wt, qkuv_bf, vt, tab,
                                                                 B_ * L_, 4 * D_, D_);
  attn_mfma<<<dim3(L_ / 128, B_ * H_), 256, 0, stream>>>(qkuv_bf, vt, amask, cmask, cbias,
                                                         gamma, beta, attng);
  gemm128_bf16<0><<<dim3(1024 / 128, 8192 / 128), 256, 0, stream>>>(attng, Wot, out,
                                                                    B_ * L_, D_, D_);
}